// Round 6
// baseline (562.612 us; speedup 1.0000x reference)
//
#include <hip/hip_runtime.h>
#include <stdint.h>

#define N_NODES 50000
#define N_EDGES 800000
#define BCAP 64    // Poisson(16): P(deg>64) ~ 1e-22 — clamp is safe
#define NPART 391  // ceil(50000/128) dst-range partitions, 128 nodes each
#define PCAP 2560  // mean 2048, sigma~45 -> +11 sigma

typedef __attribute__((ext_vector_type(8))) short bf16x8;
typedef __attribute__((ext_vector_type(4))) float f32x4;

__device__ __forceinline__ float bf2f(unsigned short u) {
    return __builtin_bit_cast(float, (unsigned int)u << 16);
}
__device__ __forceinline__ unsigned short f2bf(float f) {  // RNE, finite inputs
    unsigned int u = __builtin_bit_cast(unsigned int, f);
    u += 0x7fffu + ((u >> 16) & 1u);
    return (unsigned short)(u >> 16);
}

// fp8 e4m3fn, non-negative inputs only (post-relu). Manual to avoid builtin-name risk.
__device__ __forceinline__ unsigned char f2fp8(float f) {
    f = fminf(f, 448.f);
    if (f < 0.015625f) {                                  // subnormal: step 2^-9
        return (unsigned char)(int)__builtin_rintf(f * 512.f);  // 0..8 (8 == 2^-6, still valid)
    }
    unsigned int u = __builtin_bit_cast(unsigned int, f);
    u += 0x7FFFFu + ((u >> 20) & 1u);                     // RNE to 3 mantissa bits
    return (unsigned char)((u >> 20) - 960u);             // ((exp-120)<<3)|mant3
}
__device__ __forceinline__ void accf8x4(float* a, unsigned int w) {  // 4 packed fp8 -> a[0..3]
#pragma unroll
    for (int b = 0; b < 4; b++) {
        unsigned int c = (w >> (8 * b)) & 0xFFu;
        float n = __builtin_bit_cast(float, 0x3C000000u + (c << 20));  // normal: 1.m * 2^(e-7)
        a[b] += (c < 8u) ? (float)c * 0.001953125f : n;                // subnormal: c * 2^-9
    }
}

__device__ __forceinline__ void load_lds16(const void* g, void* l) {
    __builtin_amdgcn_global_load_lds(
        (const __attribute__((address_space(1))) void*)(uintptr_t)g,
        (__attribute__((address_space(3))) void*)(unsigned int)(uintptr_t)l,
        16, 0, 0);
}

// ---------------- build pass A: append edges into dst-range partitions ----------------
// Appends are concurrently dense (hot cursor regions fill whole 64B lines before
// eviction) — replaces R4/R5's 800k random 4B writes (50MB line-writeback, ~60us).
__global__ __launch_bounds__(256) void part_append_k(
    const int* __restrict__ src, const int* __restrict__ dst,
    int* __restrict__ pcnt, uint2* __restrict__ pbuf, int nedges)
{
    int e = blockIdx.x * 256 + threadIdx.x;
    if (e >= nedges) return;
    int s = src[e], d = dst[e];
    int part = d >> 7;                       // 128 dst nodes per partition
    int pos = atomicAdd(&pcnt[part], 1);
    if (pos < PCAP) pbuf[(size_t)part * PCAP + pos] = make_uint2((unsigned)s, (unsigned)d);
}

// ---------------- build pass B: per-partition local bucket fill (LDS counters) --------
// One block owns 128 dst nodes; bucket region = 128*256B = 32KB, hot in L2 while the
// block runs -> dense writebacks. No global atomics on per-node counters.
__global__ __launch_bounds__(256) void part_bucket_k(
    const int* __restrict__ pcnt, const uint2* __restrict__ pbuf,
    int* __restrict__ bucket, int* __restrict__ degtot, float* __restrict__ invdeg)
{
    __shared__ int lcnt[128];
    int part = blockIdx.x, tid = threadIdx.x;
    if (tid < 128) lcnt[tid] = 0;
    __syncthreads();
    int n = pcnt[part];
    if (n > PCAP) n = PCAP;
    const uint2* pb = pbuf + (size_t)part * PCAP;
    for (int i = tid; i < n; i += 256) {
        uint2 pr = pb[i];
        int d = (int)pr.y;
        int p = atomicAdd(&lcnt[d & 127], 1);
        if (p < BCAP) bucket[(size_t)d * BCAP + p] = (int)pr.x;
    }
    __syncthreads();
    if (tid < 128) {
        int node = part * 128 + tid;
        if (node < N_NODES) {
            int c = lcnt[tid];
            degtot[node] = (c > BCAP) ? BCAP : c;
            invdeg[node] = 1.0f / (float)(c > 1 ? c : 1);
        }
    }
}

// ---------------- converts ----------------
__global__ __launch_bounds__(256) void cvt_x_k(
    const float* __restrict__ x, unsigned short* __restrict__ dst)
{
    int tid = blockIdx.x * 256 + threadIdx.x;  // one per 4 floats
    if (tid >= N_NODES * 32) return;
    int row = tid >> 5, c = (tid & 31) * 4;
    float4 v = *(const float4*)(x + (size_t)row * 128 + c);
    ushort4 o;
    o.x = f2bf(v.x); o.y = f2bf(v.y); o.z = f2bf(v.z); o.w = f2bf(v.w);
    *(ushort4*)(dst + (size_t)row * 256 + 128 + c) = o;
}

__global__ __launch_bounds__(256) void cvt_w_k(
    const float* __restrict__ wl, const float* __restrict__ wr,
    unsigned short* __restrict__ dst, int Keach)
{
    int tid = blockIdx.x * 256 + threadIdx.x;
    if (tid >= 256 * 2 * Keach) return;
    int n = tid / (2 * Keach), k = tid - n * 2 * Keach;
    float v = (k < Keach) ? wl[(size_t)n * Keach + k]
                          : wr[(size_t)n * Keach + (k - Keach)];
    dst[tid] = f2bf(v);
}

// ---------------- layer-1 aggregation: bf16 gather (256B rows), 4 edges/iter --------
// All __shfl with full wave active (R3 lesson); tail is wave-uniform + clamped index.
__device__ __forceinline__ void acc8(float* a, uint4 u) {
    a[0] += bf2f((unsigned short)u.x); a[1] += bf2f((unsigned short)(u.x >> 16));
    a[2] += bf2f((unsigned short)u.y); a[3] += bf2f((unsigned short)(u.y >> 16));
    a[4] += bf2f((unsigned short)u.z); a[5] += bf2f((unsigned short)(u.z >> 16));
    a[6] += bf2f((unsigned short)u.w); a[7] += bf2f((unsigned short)(u.w >> 16));
}

__global__ __launch_bounds__(256) void agg1_k(
    const unsigned short* __restrict__ feat,  // x table rows: stride 256 ushorts, 128 dims
    const int* __restrict__ bucket, const int* __restrict__ degtot,
    const float* __restrict__ invdeg,
    unsigned short* __restrict__ outmsg)      // msg1: stride 256 ushorts, dims 0..127
{
    int wv = threadIdx.x >> 6, lane = threadIdx.x & 63;
    int node = blockIdx.x * 4 + wv;
    if (node >= N_NODES) return;
    int deg = degtot[node];
    int idx0 = bucket[(size_t)node * BCAP + lane];
    const int sub = lane >> 4;         // edge slot within group of 4
    const int col = lane & 15;         // 16B chunk of the 256B row

    float acc[8] = {};
    auto rowp = [&](int s) { return (const uint4*)(feat + (size_t)s * 256 + col * 8); };

    int j = 0;
    for (; j + 16 <= deg; j += 16) {
        int s0 = __shfl(idx0, j + sub),     s1 = __shfl(idx0, j + 4 + sub);
        int s2 = __shfl(idx0, j + 8 + sub), s3 = __shfl(idx0, j + 12 + sub);
        uint4 u0 = *rowp(s0), u1 = *rowp(s1), u2 = *rowp(s2), u3 = *rowp(s3);
        acc8(acc, u0); acc8(acc, u1); acc8(acc, u2); acc8(acc, u3);
    }
    for (; j + 8 <= deg; j += 8) {
        int s0 = __shfl(idx0, j + sub), s1 = __shfl(idx0, j + 4 + sub);
        uint4 u0 = *rowp(s0), u1 = *rowp(s1);
        acc8(acc, u0); acc8(acc, u1);
    }
    for (; j + 4 <= deg; j += 4) {
        uint4 u0 = *rowp(__shfl(idx0, j + sub));
        acc8(acc, u0);
    }
    if (j < deg) {                      // wave-uniform guard
        int e = j + sub;
        int ec = (e < deg) ? e : (deg - 1);
        uint4 u0 = *rowp(__shfl(idx0, ec));
        if (e < deg) acc8(acc, u0);
    }
#pragma unroll
    for (int stride = 32; stride >= 16; stride >>= 1)
#pragma unroll
        for (int v = 0; v < 8; v++) acc[v] += __shfl_xor(acc[v], stride);

    if (lane < 16) {
        float s = invdeg[node];
        uint4 o;
        o.x = (unsigned int)f2bf(acc[0] * s) | ((unsigned int)f2bf(acc[1] * s) << 16);
        o.y = (unsigned int)f2bf(acc[2] * s) | ((unsigned int)f2bf(acc[3] * s) << 16);
        o.z = (unsigned int)f2bf(acc[4] * s) | ((unsigned int)f2bf(acc[5] * s) << 16);
        o.w = (unsigned int)f2bf(acc[6] * s) | ((unsigned int)f2bf(acc[7] * s) << 16);
        *(uint4*)(outmsg + (size_t)node * 256 + lane * 8) = o;
    }
}

// ---------------- layer-2 aggregation: fp8 gather (256B rows = 256 dims), 4 edges/iter
__device__ __forceinline__ void acc16f8(float* a, uint4 u) {
    accf8x4(a + 0, u.x); accf8x4(a + 4, u.y); accf8x4(a + 8, u.z); accf8x4(a + 12, u.w);
}

__global__ __launch_bounds__(256) void agg2_k(
    const unsigned char* __restrict__ hf8,    // h table fp8: 256B rows
    const int* __restrict__ bucket, const int* __restrict__ degtot,
    const float* __restrict__ invdeg,
    unsigned short* __restrict__ outmsg)      // msg2: stride 512 ushorts, dims 0..255
{
    int wv = threadIdx.x >> 6, lane = threadIdx.x & 63;
    int node = blockIdx.x * 4 + wv;
    if (node >= N_NODES) return;
    int deg = degtot[node];
    int idx0 = bucket[(size_t)node * BCAP + lane];
    const int sub = lane >> 4;
    const int col = lane & 15;

    float acc[16] = {};
    auto rowp = [&](int s) { return (const uint4*)(hf8 + (size_t)s * 256 + col * 16); };

    int j = 0;
    for (; j + 16 <= deg; j += 16) {
        int s0 = __shfl(idx0, j + sub),     s1 = __shfl(idx0, j + 4 + sub);
        int s2 = __shfl(idx0, j + 8 + sub), s3 = __shfl(idx0, j + 12 + sub);
        uint4 u0 = *rowp(s0), u1 = *rowp(s1), u2 = *rowp(s2), u3 = *rowp(s3);
        acc16f8(acc, u0); acc16f8(acc, u1); acc16f8(acc, u2); acc16f8(acc, u3);
    }
    for (; j + 8 <= deg; j += 8) {
        int s0 = __shfl(idx0, j + sub), s1 = __shfl(idx0, j + 4 + sub);
        uint4 u0 = *rowp(s0), u1 = *rowp(s1);
        acc16f8(acc, u0); acc16f8(acc, u1);
    }
    for (; j + 4 <= deg; j += 4) {
        uint4 u0 = *rowp(__shfl(idx0, j + sub));
        acc16f8(acc, u0);
    }
    if (j < deg) {
        int e = j + sub;
        int ec = (e < deg) ? e : (deg - 1);
        uint4 u0 = *rowp(__shfl(idx0, ec));
        if (e < deg) acc16f8(acc, u0);
    }
#pragma unroll
    for (int stride = 32; stride >= 16; stride >>= 1)
#pragma unroll
        for (int v = 0; v < 16; v++) acc[v] += __shfl_xor(acc[v], stride);

    if (lane < 16) {
        float s = invdeg[node];
        unsigned int o[8];
#pragma unroll
        for (int v = 0; v < 8; v++)
            o[v] = (unsigned int)f2bf(acc[2 * v] * s) | ((unsigned int)f2bf(acc[2 * v + 1] * s) << 16);
        unsigned short* wp = outmsg + (size_t)node * 512 + lane * 16;
        *(uint4*)(wp)     = make_uint4(o[0], o[1], o[2], o[3]);
        *(uint4*)(wp + 8) = make_uint4(o[4], o[5], o[6], o[7]);
    }
}

// ---------------- bf16 MFMA GEMM: C = relu(A(MxK) * W(256xK)^T + bias) ----------------
// 128x128 block tile, 4 waves, 2x8 16x16x32 MFMA tiles per wave. Optional fp8 side-store.
template <bool BF16OUT, bool WRITE_FP8>
__global__ __launch_bounds__(256) void gemm_k(
    const unsigned short* __restrict__ A, const unsigned short* __restrict__ W,
    const float* __restrict__ bias, void* __restrict__ outp, int outStride,
    unsigned char* __restrict__ hf8, int M, int K)
{
    __shared__ __align__(16) char smem[(128 + 128) * 64];  // 16 KB
    const int t = threadIdx.x;
    const int w = t >> 6, lane = t & 63;
    const int quad = lane >> 4, l15 = lane & 15;
    const int row0 = blockIdx.x * 128;
    const int col0 = blockIdx.y * 128;

    f32x4 acc[2][8] = {};

    for (int ks = 0; ks < K; ks += 32) {
#pragma unroll
        for (int j = 0; j < 4; j++) {
            int call = w * 4 + j;        // 0..15, wave-uniform A/W split at 8
            int ci = call * 64 + lane;   // chunk id 0..1023
            const unsigned short* g;
            if (call < 8) {              // A chunks
                int rg = row0 + (ci >> 2);
                if (rg > M - 1) rg = M - 1;
                g = A + (size_t)rg * K + ks + (ci & 3) * 8;
            } else {                     // W chunks
                int c2 = ci - 512;
                g = W + (size_t)(col0 + (c2 >> 2)) * K + ks + (c2 & 3) * 8;
            }
            load_lds16(g, smem + ci * 16);
        }
        __syncthreads();

        const char* Ab = smem + (w * 32 + l15) * 64 + quad * 16;
        const char* Wb = smem + 8192 + l15 * 64 + quad * 16;
        bf16x8 af0 = *(const bf16x8*)(Ab);
        bf16x8 af1 = *(const bf16x8*)(Ab + 1024);
#pragma unroll
        for (int tt = 0; tt < 8; tt++) {
            bf16x8 bfr = *(const bf16x8*)(Wb + tt * 1024);
            acc[0][tt] = __builtin_amdgcn_mfma_f32_16x16x32_bf16(af0, bfr, acc[0][tt], 0, 0, 0);
            acc[1][tt] = __builtin_amdgcn_mfma_f32_16x16x32_bf16(af1, bfr, acc[1][tt], 0, 0, 0);
        }
        __syncthreads();
    }

#pragma unroll
    for (int g = 0; g < 2; g++) {
#pragma unroll
        for (int tt = 0; tt < 8; tt++) {
            int col = col0 + tt * 16 + l15;
            float bv = bias[col];
#pragma unroll
            for (int i = 0; i < 4; i++) {
                int row = row0 + w * 32 + g * 16 + quad * 4 + i;  // C/D: col=lane&15, row=quad*4+reg
                if (row < M) {
                    float v = fmaxf(acc[g][tt][i] + bv, 0.f);
                    size_t off = (size_t)row * outStride + col;
                    if constexpr (BF16OUT) ((unsigned short*)outp)[off] = f2bf(v);
                    else                   ((float*)outp)[off] = v;
                    if constexpr (WRITE_FP8) hf8[(size_t)row * 256 + col] = f2fp8(v);
                }
            }
        }
    }
}

extern "C" void kernel_launch(void* const* d_in, const int* in_sizes, int n_in,
                              void* d_out, int out_size, void* d_ws, size_t ws_size,
                              hipStream_t stream)
{
    const float* x   = (const float*)d_in[0];
    const int*   ei  = (const int*)d_in[1];
    const float* wl1 = (const float*)d_in[2];
    const float* bl1 = (const float*)d_in[3];
    const float* wr1 = (const float*)d_in[4];
    const float* wl2 = (const float*)d_in[5];
    const float* bl2 = (const float*)d_in[6];
    const float* wr2 = (const float*)d_in[7];
    float* out = (float*)d_out;
    const int* src = ei;
    const int* dst = ei + N_EDGES;

    char* ws = (char*)d_ws;
    size_t off = 0;
    auto alloc = [&](size_t bytes) -> void* {
        void* p = ws + off;
        off = (off + bytes + 255) & ~(size_t)255;
        return p;
    };
    int*            pcnt   = (int*)           alloc((size_t)NPART * 4);
    uint2*          pbuf   = (uint2*)         alloc((size_t)NPART * PCAP * 8);   // 8.0 MB
    int*            bucket = (int*)           alloc((size_t)N_NODES * BCAP * 4); // 12.8 MB
    int*            degtot = (int*)           alloc((size_t)N_NODES * 4);
    float*          invdeg = (float*)         alloc((size_t)N_NODES * 4);
    unsigned short* Acat1  = (unsigned short*)alloc((size_t)N_NODES * 256 * 2);  // [msg1|x]
    unsigned short* Acat2  = (unsigned short*)alloc((size_t)N_NODES * 512 * 2);  // [msg2|h]
    unsigned char*  hf8    = (unsigned char*) alloc((size_t)N_NODES * 256);      // h fp8 table
    unsigned short* Wcat1  = (unsigned short*)alloc((size_t)256 * 256 * 2);
    unsigned short* Wcat2  = (unsigned short*)alloc((size_t)256 * 512 * 2);

    hipMemsetAsync(pcnt, 0, (size_t)NPART * 4, stream);
    part_append_k<<<(N_EDGES + 255) / 256, 256, 0, stream>>>(src, dst, pcnt, pbuf, N_EDGES);
    part_bucket_k<<<NPART, 256, 0, stream>>>(pcnt, pbuf, bucket, degtot, invdeg);

    cvt_x_k<<<(N_NODES * 32 + 255) / 256, 256, 0, stream>>>(x, Acat1);
    cvt_w_k<<<(256 * 256 + 255) / 256, 256, 0, stream>>>(wl1, wr1, Wcat1, 128);
    cvt_w_k<<<(256 * 512 + 255) / 256, 256, 0, stream>>>(wl2, wr2, Wcat2, 256);

    // Layer 1: agg x_bf16 -> msg1; h = relu(Acat1 @ Wcat1^T + b) -> Acat2 right half + hf8
    agg1_k<<<(N_NODES + 3) / 4, 256, 0, stream>>>(
        Acat1 + 128, bucket, degtot, invdeg, Acat1);
    gemm_k<true, true><<<dim3((N_NODES + 127) / 128, 2), 256, 0, stream>>>(
        Acat1, Wcat1, bl1, (void*)(Acat2 + 256), 512, hf8, N_NODES, 256);

    // Layer 2: agg hf8 -> msg2; out = relu(Acat2 @ Wcat2^T + b) fp32
    agg2_k<<<(N_NODES + 3) / 4, 256, 0, stream>>>(
        hf8, bucket, degtot, invdeg, Acat2);
    gemm_k<false, false><<<dim3((N_NODES + 127) / 128, 2), 256, 0, stream>>>(
        Acat2, Wcat2, bl2, (void*)out, 256, nullptr, N_NODES, 512);
}

// Round 7
// 318.636 us; speedup vs baseline: 1.7657x; 1.7657x over previous
//
#include <hip/hip_runtime.h>
#include <stdint.h>

#define N_NODES 50000
#define N_EDGES 800000
#define BCAP 64    // Poisson(16): P(deg>64) ~ 1e-22 — clamp is safe
#define NPART 782  // ceil(50000/64) dst-range partitions, 64 nodes each
#define NSUB 4     // sub-lists per partition -> 3128 cursors, one 64B line each
#define SCAP 384   // per-sub-list capacity: Poisson(256) + 8 sigma

typedef __attribute__((ext_vector_type(8))) short bf16x8;
typedef __attribute__((ext_vector_type(4))) float f32x4;

__device__ __forceinline__ float bf2f(unsigned short u) {
    return __builtin_bit_cast(float, (unsigned int)u << 16);
}
__device__ __forceinline__ unsigned short f2bf(float f) {  // RNE, finite inputs
    unsigned int u = __builtin_bit_cast(unsigned int, f);
    u += 0x7fffu + ((u >> 16) & 1u);
    return (unsigned short)(u >> 16);
}

// fp8 e4m3fn, non-negative inputs only (post-relu). Validated in R6 (absmax 0.0156).
__device__ __forceinline__ unsigned char f2fp8(float f) {
    f = fminf(f, 448.f);
    if (f < 0.015625f) {                                  // subnormal: step 2^-9
        return (unsigned char)(int)__builtin_rintf(f * 512.f);
    }
    unsigned int u = __builtin_bit_cast(unsigned int, f);
    u += 0x7FFFFu + ((u >> 20) & 1u);                     // RNE to 3 mantissa bits
    return (unsigned char)((u >> 20) - 960u);             // ((exp-120)<<3)|mant3
}
__device__ __forceinline__ void accf8x4(float* a, unsigned int w) {  // 4 packed fp8 -> a[0..3]
#pragma unroll
    for (int b = 0; b < 4; b++) {
        unsigned int c = (w >> (8 * b)) & 0xFFu;
        float n = __builtin_bit_cast(float, 0x3C000000u + (c << 20));  // normal: 1.m * 2^(e-7)
        a[b] += (c < 8u) ? (float)c * 0.001953125f : n;                // subnormal: c * 2^-9
    }
}

__device__ __forceinline__ void load_lds16(const void* g, void* l) {
    __builtin_amdgcn_global_load_lds(
        (const __attribute__((address_space(1))) void*)(uintptr_t)g,
        (__attribute__((address_space(3))) void*)(unsigned int)(uintptr_t)l,
        16, 0, 0);
}

// ---------------- build pass A: append edges into (partition,sub) lists --------------
// R6 lesson: same-line atomic serialization ~8.8ns/op; cost ∝ ops per cursor LINE.
// 3128 cursors, each padded to a private 64B line -> 256 ops/line (~2.2us/line, parallel
// across L2 slices). Entries are 4B: (d&63)<<16 | src (src<65536).
__global__ __launch_bounds__(256) void part_append_k(
    const int* __restrict__ src, const int* __restrict__ dst,
    int* __restrict__ pcnt, unsigned int* __restrict__ pbuf, int nedges)
{
    int e = blockIdx.x * 256 + threadIdx.x;
    if (e >= nedges) return;
    int s = src[e], d = dst[e];
    int cidx = (d >> 6) * NSUB + (e & (NSUB - 1));
    int pos = atomicAdd(&pcnt[cidx * 16], 1);   // *16: one 64B line per cursor
    if (pos < SCAP)
        pbuf[(size_t)cidx * SCAP + pos] = ((unsigned)(d & 63) << 16) | (unsigned)s;
}

// ---------------- build pass B: per-partition local bucket fill (LDS counters) --------
// One block owns 64 dst nodes; its bucket region = 64*256B = 16KB, hot in L2 while the
// block runs -> dense writebacks. No global atomics.
__global__ __launch_bounds__(256) void part_bucket_k(
    const int* __restrict__ pcnt, const unsigned int* __restrict__ pbuf,
    int* __restrict__ bucket, int* __restrict__ degtot, float* __restrict__ invdeg)
{
    __shared__ int lcnt[64];
    int part = blockIdx.x, tid = threadIdx.x;
    if (tid < 64) lcnt[tid] = 0;
    __syncthreads();
#pragma unroll
    for (int sub = 0; sub < NSUB; sub++) {
        int cidx = part * NSUB + sub;
        int n = pcnt[cidx * 16];
        if (n > SCAP) n = SCAP;
        const unsigned int* pb = pbuf + (size_t)cidx * SCAP;
        for (int i = tid; i < n; i += 256) {
            unsigned int en = pb[i];
            int dlow = (int)(en >> 16), s = (int)(en & 0xFFFFu);
            int p = atomicAdd(&lcnt[dlow], 1);
            if (p < BCAP) bucket[(size_t)(part * 64 + dlow) * BCAP + p] = s;
        }
    }
    __syncthreads();
    if (tid < 64) {
        int node = part * 64 + tid;
        if (node < N_NODES) {
            int c = lcnt[tid];
            degtot[node] = (c > BCAP) ? BCAP : c;
            invdeg[node] = 1.0f / (float)(c > 1 ? c : 1);
        }
    }
}

// ---------------- converts ----------------
__global__ __launch_bounds__(256) void cvt_x_k(
    const float* __restrict__ x, unsigned short* __restrict__ dst)
{
    int tid = blockIdx.x * 256 + threadIdx.x;  // one per 4 floats
    if (tid >= N_NODES * 32) return;
    int row = tid >> 5, c = (tid & 31) * 4;
    float4 v = *(const float4*)(x + (size_t)row * 128 + c);
    ushort4 o;
    o.x = f2bf(v.x); o.y = f2bf(v.y); o.z = f2bf(v.z); o.w = f2bf(v.w);
    *(ushort4*)(dst + (size_t)row * 256 + 128 + c) = o;
}

__global__ __launch_bounds__(256) void cvt_w_k(
    const float* __restrict__ wl, const float* __restrict__ wr,
    unsigned short* __restrict__ dst, int Keach)
{
    int tid = blockIdx.x * 256 + threadIdx.x;
    if (tid >= 256 * 2 * Keach) return;
    int n = tid / (2 * Keach), k = tid - n * 2 * Keach;
    float v = (k < Keach) ? wl[(size_t)n * Keach + k]
                          : wr[(size_t)n * Keach + (k - Keach)];
    dst[tid] = f2bf(v);
}

// ---------------- layer-1 aggregation: bf16 gather (256B rows), 4 edges/iter --------
__device__ __forceinline__ void acc8(float* a, uint4 u) {
    a[0] += bf2f((unsigned short)u.x); a[1] += bf2f((unsigned short)(u.x >> 16));
    a[2] += bf2f((unsigned short)u.y); a[3] += bf2f((unsigned short)(u.y >> 16));
    a[4] += bf2f((unsigned short)u.z); a[5] += bf2f((unsigned short)(u.z >> 16));
    a[6] += bf2f((unsigned short)u.w); a[7] += bf2f((unsigned short)(u.w >> 16));
}

__global__ __launch_bounds__(256) void agg1_k(
    const unsigned short* __restrict__ feat,  // x table rows: stride 256 ushorts, 128 dims
    const int* __restrict__ bucket, const int* __restrict__ degtot,
    const float* __restrict__ invdeg,
    unsigned short* __restrict__ outmsg)      // msg1: stride 256 ushorts, dims 0..127
{
    int wv = threadIdx.x >> 6, lane = threadIdx.x & 63;
    int node = blockIdx.x * 4 + wv;
    if (node >= N_NODES) return;
    int deg = degtot[node];
    int idx0 = bucket[(size_t)node * BCAP + lane];
    const int sub = lane >> 4;         // edge slot within group of 4
    const int col = lane & 15;         // 16B chunk of the 256B row

    float acc[8] = {};
    auto rowp = [&](int s) { return (const uint4*)(feat + (size_t)s * 256 + col * 8); };

    int j = 0;
    for (; j + 16 <= deg; j += 16) {
        int s0 = __shfl(idx0, j + sub),     s1 = __shfl(idx0, j + 4 + sub);
        int s2 = __shfl(idx0, j + 8 + sub), s3 = __shfl(idx0, j + 12 + sub);
        uint4 u0 = *rowp(s0), u1 = *rowp(s1), u2 = *rowp(s2), u3 = *rowp(s3);
        acc8(acc, u0); acc8(acc, u1); acc8(acc, u2); acc8(acc, u3);
    }
    for (; j + 8 <= deg; j += 8) {
        int s0 = __shfl(idx0, j + sub), s1 = __shfl(idx0, j + 4 + sub);
        uint4 u0 = *rowp(s0), u1 = *rowp(s1);
        acc8(acc, u0); acc8(acc, u1);
    }
    for (; j + 4 <= deg; j += 4) {
        uint4 u0 = *rowp(__shfl(idx0, j + sub));
        acc8(acc, u0);
    }
    if (j < deg) {                      // wave-uniform guard (R3 lesson)
        int e = j + sub;
        int ec = (e < deg) ? e : (deg - 1);
        uint4 u0 = *rowp(__shfl(idx0, ec));
        if (e < deg) acc8(acc, u0);
    }
#pragma unroll
    for (int stride = 32; stride >= 16; stride >>= 1)
#pragma unroll
        for (int v = 0; v < 8; v++) acc[v] += __shfl_xor(acc[v], stride);

    if (lane < 16) {
        float s = invdeg[node];
        uint4 o;
        o.x = (unsigned int)f2bf(acc[0] * s) | ((unsigned int)f2bf(acc[1] * s) << 16);
        o.y = (unsigned int)f2bf(acc[2] * s) | ((unsigned int)f2bf(acc[3] * s) << 16);
        o.z = (unsigned int)f2bf(acc[4] * s) | ((unsigned int)f2bf(acc[5] * s) << 16);
        o.w = (unsigned int)f2bf(acc[6] * s) | ((unsigned int)f2bf(acc[7] * s) << 16);
        *(uint4*)(outmsg + (size_t)node * 256 + lane * 8) = o;
    }
}

// ---------------- layer-2 aggregation: fp8 gather (256B rows = 256 dims), 4 edges/iter
__device__ __forceinline__ void acc16f8(float* a, uint4 u) {
    accf8x4(a + 0, u.x); accf8x4(a + 4, u.y); accf8x4(a + 8, u.z); accf8x4(a + 12, u.w);
}

__global__ __launch_bounds__(256) void agg2_k(
    const unsigned char* __restrict__ hf8,    // h table fp8: 256B rows
    const int* __restrict__ bucket, const int* __restrict__ degtot,
    const float* __restrict__ invdeg,
    unsigned short* __restrict__ outmsg)      // msg2: stride 512 ushorts, dims 0..255
{
    int wv = threadIdx.x >> 6, lane = threadIdx.x & 63;
    int node = blockIdx.x * 4 + wv;
    if (node >= N_NODES) return;
    int deg = degtot[node];
    int idx0 = bucket[(size_t)node * BCAP + lane];
    const int sub = lane >> 4;
    const int col = lane & 15;

    float acc[16] = {};
    auto rowp = [&](int s) { return (const uint4*)(hf8 + (size_t)s * 256 + col * 16); };

    int j = 0;
    for (; j + 16 <= deg; j += 16) {
        int s0 = __shfl(idx0, j + sub),     s1 = __shfl(idx0, j + 4 + sub);
        int s2 = __shfl(idx0, j + 8 + sub), s3 = __shfl(idx0, j + 12 + sub);
        uint4 u0 = *rowp(s0), u1 = *rowp(s1), u2 = *rowp(s2), u3 = *rowp(s3);
        acc16f8(acc, u0); acc16f8(acc, u1); acc16f8(acc, u2); acc16f8(acc, u3);
    }
    for (; j + 8 <= deg; j += 8) {
        int s0 = __shfl(idx0, j + sub), s1 = __shfl(idx0, j + 4 + sub);
        uint4 u0 = *rowp(s0), u1 = *rowp(s1);
        acc16f8(acc, u0); acc16f8(acc, u1);
    }
    for (; j + 4 <= deg; j += 4) {
        uint4 u0 = *rowp(__shfl(idx0, j + sub));
        acc16f8(acc, u0);
    }
    if (j < deg) {
        int e = j + sub;
        int ec = (e < deg) ? e : (deg - 1);
        uint4 u0 = *rowp(__shfl(idx0, ec));
        if (e < deg) acc16f8(acc, u0);
    }
#pragma unroll
    for (int stride = 32; stride >= 16; stride >>= 1)
#pragma unroll
        for (int v = 0; v < 16; v++) acc[v] += __shfl_xor(acc[v], stride);

    if (lane < 16) {
        float s = invdeg[node];
        unsigned int o[8];
#pragma unroll
        for (int v = 0; v < 8; v++)
            o[v] = (unsigned int)f2bf(acc[2 * v] * s) | ((unsigned int)f2bf(acc[2 * v + 1] * s) << 16);
        unsigned short* wp = outmsg + (size_t)node * 512 + lane * 16;
        *(uint4*)(wp)     = make_uint4(o[0], o[1], o[2], o[3]);
        *(uint4*)(wp + 8) = make_uint4(o[4], o[5], o[6], o[7]);
    }
}

// ---------------- bf16 MFMA GEMM: C = relu(A(MxK) * W(256xK)^T + bias) ----------------
// 128x128 block tile, 4 waves, 2x8 16x16x32 MFMA tiles per wave. Optional fp8 side-store.
template <bool BF16OUT, bool WRITE_FP8>
__global__ __launch_bounds__(256) void gemm_k(
    const unsigned short* __restrict__ A, const unsigned short* __restrict__ W,
    const float* __restrict__ bias, void* __restrict__ outp, int outStride,
    unsigned char* __restrict__ hf8, int M, int K)
{
    __shared__ __align__(16) char smem[(128 + 128) * 64];  // 16 KB
    const int t = threadIdx.x;
    const int w = t >> 6, lane = t & 63;
    const int quad = lane >> 4, l15 = lane & 15;
    const int row0 = blockIdx.x * 128;
    const int col0 = blockIdx.y * 128;

    f32x4 acc[2][8] = {};

    for (int ks = 0; ks < K; ks += 32) {
#pragma unroll
        for (int j = 0; j < 4; j++) {
            int call = w * 4 + j;        // 0..15, wave-uniform A/W split at 8
            int ci = call * 64 + lane;   // chunk id 0..1023
            const unsigned short* g;
            if (call < 8) {              // A chunks
                int rg = row0 + (ci >> 2);
                if (rg > M - 1) rg = M - 1;
                g = A + (size_t)rg * K + ks + (ci & 3) * 8;
            } else {                     // W chunks
                int c2 = ci - 512;
                g = W + (size_t)(col0 + (c2 >> 2)) * K + ks + (c2 & 3) * 8;
            }
            load_lds16(g, smem + ci * 16);
        }
        __syncthreads();

        const char* Ab = smem + (w * 32 + l15) * 64 + quad * 16;
        const char* Wb = smem + 8192 + l15 * 64 + quad * 16;
        bf16x8 af0 = *(const bf16x8*)(Ab);
        bf16x8 af1 = *(const bf16x8*)(Ab + 1024);
#pragma unroll
        for (int tt = 0; tt < 8; tt++) {
            bf16x8 bfr = *(const bf16x8*)(Wb + tt * 1024);
            acc[0][tt] = __builtin_amdgcn_mfma_f32_16x16x32_bf16(af0, bfr, acc[0][tt], 0, 0, 0);
            acc[1][tt] = __builtin_amdgcn_mfma_f32_16x16x32_bf16(af1, bfr, acc[1][tt], 0, 0, 0);
        }
        __syncthreads();
    }

#pragma unroll
    for (int g = 0; g < 2; g++) {
#pragma unroll
        for (int tt = 0; tt < 8; tt++) {
            int col = col0 + tt * 16 + l15;
            float bv = bias[col];
#pragma unroll
            for (int i = 0; i < 4; i++) {
                int row = row0 + w * 32 + g * 16 + quad * 4 + i;  // C/D: col=lane&15, row=quad*4+reg
                if (row < M) {
                    float v = fmaxf(acc[g][tt][i] + bv, 0.f);
                    size_t off = (size_t)row * outStride + col;
                    if constexpr (BF16OUT) ((unsigned short*)outp)[off] = f2bf(v);
                    else                   ((float*)outp)[off] = v;
                    if constexpr (WRITE_FP8) hf8[(size_t)row * 256 + col] = f2fp8(v);
                }
            }
        }
    }
}

extern "C" void kernel_launch(void* const* d_in, const int* in_sizes, int n_in,
                              void* d_out, int out_size, void* d_ws, size_t ws_size,
                              hipStream_t stream)
{
    const float* x   = (const float*)d_in[0];
    const int*   ei  = (const int*)d_in[1];
    const float* wl1 = (const float*)d_in[2];
    const float* bl1 = (const float*)d_in[3];
    const float* wr1 = (const float*)d_in[4];
    const float* wl2 = (const float*)d_in[5];
    const float* bl2 = (const float*)d_in[6];
    const float* wr2 = (const float*)d_in[7];
    float* out = (float*)d_out;
    const int* src = ei;
    const int* dst = ei + N_EDGES;

    char* ws = (char*)d_ws;
    size_t off = 0;
    auto alloc = [&](size_t bytes) -> void* {
        void* p = ws + off;
        off = (off + bytes + 255) & ~(size_t)255;
        return p;
    };
    int*            pcnt   = (int*)           alloc((size_t)NPART * NSUB * 16 * 4); // 200KB, 1 line/cursor
    unsigned int*   pbuf   = (unsigned int*)  alloc((size_t)NPART * NSUB * SCAP * 4); // 4.8 MB
    int*            bucket = (int*)           alloc((size_t)NPART * 64 * BCAP * 4);   // 12.8 MB
    int*            degtot = (int*)           alloc((size_t)N_NODES * 4);
    float*          invdeg = (float*)         alloc((size_t)N_NODES * 4);
    unsigned short* Acat1  = (unsigned short*)alloc((size_t)N_NODES * 256 * 2);  // [msg1|x]
    unsigned short* Acat2  = (unsigned short*)alloc((size_t)N_NODES * 512 * 2);  // [msg2|h]
    unsigned char*  hf8    = (unsigned char*) alloc((size_t)N_NODES * 256);      // h fp8 table
    unsigned short* Wcat1  = (unsigned short*)alloc((size_t)256 * 256 * 2);
    unsigned short* Wcat2  = (unsigned short*)alloc((size_t)256 * 512 * 2);

    hipMemsetAsync(pcnt, 0, (size_t)NPART * NSUB * 16 * 4, stream);
    part_append_k<<<(N_EDGES + 255) / 256, 256, 0, stream>>>(src, dst, pcnt, pbuf, N_EDGES);
    part_bucket_k<<<NPART, 256, 0, stream>>>(pcnt, pbuf, bucket, degtot, invdeg);

    cvt_x_k<<<(N_NODES * 32 + 255) / 256, 256, 0, stream>>>(x, Acat1);
    cvt_w_k<<<(256 * 256 + 255) / 256, 256, 0, stream>>>(wl1, wr1, Wcat1, 128);
    cvt_w_k<<<(256 * 512 + 255) / 256, 256, 0, stream>>>(wl2, wr2, Wcat2, 256);

    // Layer 1: agg x_bf16 -> msg1; h = relu(Acat1 @ Wcat1^T + b) -> Acat2 right half + hf8
    agg1_k<<<(N_NODES + 3) / 4, 256, 0, stream>>>(
        Acat1 + 128, bucket, degtot, invdeg, Acat1);
    gemm_k<true, true><<<dim3((N_NODES + 127) / 128, 2), 256, 0, stream>>>(
        Acat1, Wcat1, bl1, (void*)(Acat2 + 256), 512, hf8, N_NODES, 256);

    // Layer 2: agg hf8 -> msg2; out = relu(Acat2 @ Wcat2^T + b) fp32
    agg2_k<<<(N_NODES + 3) / 4, 256, 0, stream>>>(
        hf8, bucket, degtot, invdeg, Acat2);
    gemm_k<false, false><<<dim3((N_NODES + 127) / 128, 2), 256, 0, stream>>>(
        Acat2, Wcat2, bl2, (void*)out, 256, nullptr, N_NODES, 512);
}

// Round 8
// 288.174 us; speedup vs baseline: 1.9523x; 1.1057x over previous
//
#include <hip/hip_runtime.h>
#include <hip/hip_fp16.h>
#include <stdint.h>

#define N_NODES 50000
#define N_EDGES 800000
#define BCAP 64    // Poisson(16): P(deg>64) ~ 1e-22 — clamp is safe
#define NPART 782  // ceil(50000/64) dst-range partitions, 64 nodes each
#define NSUB 4     // sub-lists per partition -> 3128 cursors, one 64B line each
#define SCAP 384   // per-sub-list capacity: Poisson(256) + 8 sigma

typedef _Float16 f16x8 __attribute__((ext_vector_type(8)));
typedef __attribute__((ext_vector_type(4))) float f32x4;

__device__ __forceinline__ unsigned short f2h(float f) {
    return __builtin_bit_cast(unsigned short, (_Float16)f);
}

// fp8 e4m3 with +2^-6 offset (inputs >= 0 post-relu): code is ALWAYS normal (c>=8),
// so decode is exactly linear in bits: f16 = (c<<7) + 0x2000. The +2^-6 telescopes
// to a per-node constant removed after reduction. v=0 roundtrips exactly.
__device__ __forceinline__ unsigned char f2fp8o(float v) {
    v = fminf(v, 440.f) + 0.015625f;
    unsigned int u = __builtin_bit_cast(unsigned int, v);
    u += 0x7FFFFu + ((u >> 20) & 1u);            // RNE to 3 mantissa bits
    return (unsigned char)((u >> 20) - 960u);    // ((exp-120)<<3)|mant3, 8..126
}

__device__ __forceinline__ void load_lds16(const void* g, void* l) {
    __builtin_amdgcn_global_load_lds(
        (const __attribute__((address_space(1))) void*)(uintptr_t)g,
        (__attribute__((address_space(3))) void*)(unsigned int)(uintptr_t)l,
        16, 0, 0);
}

// ---------------- build pass A: append edges into (partition,sub) lists --------------
// R6 lesson: same-line atomic serialization ~8.8ns/op; cost ∝ ops per cursor LINE.
// 3128 cursors, one private 64B line each -> ~256 ops/line, lines served in parallel.
__global__ __launch_bounds__(256) void part_append_k(
    const int* __restrict__ src, const int* __restrict__ dst,
    int* __restrict__ pcnt, unsigned int* __restrict__ pbuf, int nedges)
{
    int e = blockIdx.x * 256 + threadIdx.x;
    if (e >= nedges) return;
    int s = src[e], d = dst[e];
    int cidx = (d >> 6) * NSUB + (e & (NSUB - 1));
    int pos = atomicAdd(&pcnt[cidx * 16], 1);   // *16: one 64B line per cursor
    if (pos < SCAP)
        pbuf[(size_t)cidx * SCAP + pos] = ((unsigned)(d & 63) << 16) | (unsigned)s;
}

// ---------------- build pass B: per-partition local bucket fill (LDS counters) --------
__global__ __launch_bounds__(256) void part_bucket_k(
    const int* __restrict__ pcnt, const unsigned int* __restrict__ pbuf,
    int* __restrict__ bucket, int* __restrict__ degtot, float* __restrict__ invdeg)
{
    __shared__ int lcnt[64];
    int part = blockIdx.x, tid = threadIdx.x;
    if (tid < 64) lcnt[tid] = 0;
    __syncthreads();
#pragma unroll
    for (int sub = 0; sub < NSUB; sub++) {
        int cidx = part * NSUB + sub;
        int n = pcnt[cidx * 16];
        if (n > SCAP) n = SCAP;
        const unsigned int* pb = pbuf + (size_t)cidx * SCAP;
        for (int i = tid; i < n; i += 256) {
            unsigned int en = pb[i];
            int dlow = (int)(en >> 16), s = (int)(en & 0xFFFFu);
            int p = atomicAdd(&lcnt[dlow], 1);
            if (p < BCAP) bucket[(size_t)(part * 64 + dlow) * BCAP + p] = s;
        }
    }
    __syncthreads();
    if (tid < 64) {
        int node = part * 64 + tid;
        if (node < N_NODES) {
            int c = lcnt[tid];
            degtot[node] = (c > BCAP) ? BCAP : c;
            invdeg[node] = 1.0f / (float)(c > 1 ? c : 1);
        }
    }
}

// ---------------- converts (f16 tables) ----------------
__global__ __launch_bounds__(256) void cvt_x_k(
    const float* __restrict__ x, unsigned short* __restrict__ dst)
{
    int tid = blockIdx.x * 256 + threadIdx.x;  // one per 4 floats
    if (tid >= N_NODES * 32) return;
    int row = tid >> 5, c = (tid & 31) * 4;
    float4 v = *(const float4*)(x + (size_t)row * 128 + c);
    ushort4 o;
    o.x = f2h(v.x); o.y = f2h(v.y); o.z = f2h(v.z); o.w = f2h(v.w);
    *(ushort4*)(dst + (size_t)row * 256 + 128 + c) = o;
}

__global__ __launch_bounds__(256) void cvt_w_k(
    const float* __restrict__ wl, const float* __restrict__ wr,
    unsigned short* __restrict__ dst, int Keach)
{
    int tid = blockIdx.x * 256 + threadIdx.x;
    if (tid >= 256 * 2 * Keach) return;
    int n = tid / (2 * Keach), k = tid - n * 2 * Keach;
    float v = (k < Keach) ? wl[(size_t)n * Keach + k]
                          : wr[(size_t)n * Keach + (k - Keach)];
    dst[tid] = f2h(v);
}

// ---------------- layer-1 aggregation: f16 gather, packed-f16 accumulate ------------
// Loaded uint4 = 8 f16 dims; accumulate with 4 v_pk_add_f16 — zero decode cost.
// All __shfl with full wave active (R3 lesson); tail is wave-uniform + clamped.
__device__ __forceinline__ void acch4(__half2* a, uint4 u) {
    a[0] = __hadd2(a[0], __builtin_bit_cast(__half2, u.x));
    a[1] = __hadd2(a[1], __builtin_bit_cast(__half2, u.y));
    a[2] = __hadd2(a[2], __builtin_bit_cast(__half2, u.z));
    a[3] = __hadd2(a[3], __builtin_bit_cast(__half2, u.w));
}

__global__ __launch_bounds__(256) void agg1_k(
    const unsigned short* __restrict__ feat,  // f16 x table: stride 256, dims in cols 0..127 of ptr
    const int* __restrict__ bucket, const int* __restrict__ degtot,
    const float* __restrict__ invdeg,
    unsigned short* __restrict__ outmsg)      // msg1 f16: stride 256, dims 0..127
{
    int wv = threadIdx.x >> 6, lane = threadIdx.x & 63;
    int node = blockIdx.x * 4 + wv;
    if (node >= N_NODES) return;
    int deg = degtot[node];
    int idx0 = bucket[(size_t)node * BCAP + lane];
    const int sub = lane >> 4;         // edge slot within group of 4
    const int col = lane & 15;         // 16B chunk of the 256B row

    __half2 acc[4] = {};
    auto rowp = [&](int s) { return (const uint4*)(feat + (size_t)s * 256 + col * 8); };

    int j = 0;
    for (; j + 16 <= deg; j += 16) {
        int s0 = __shfl(idx0, j + sub),     s1 = __shfl(idx0, j + 4 + sub);
        int s2 = __shfl(idx0, j + 8 + sub), s3 = __shfl(idx0, j + 12 + sub);
        uint4 u0 = *rowp(s0), u1 = *rowp(s1), u2 = *rowp(s2), u3 = *rowp(s3);
        acch4(acc, u0); acch4(acc, u1); acch4(acc, u2); acch4(acc, u3);
    }
    for (; j + 8 <= deg; j += 8) {
        int s0 = __shfl(idx0, j + sub), s1 = __shfl(idx0, j + 4 + sub);
        uint4 u0 = *rowp(s0), u1 = *rowp(s1);
        acch4(acc, u0); acch4(acc, u1);
    }
    for (; j + 4 <= deg; j += 4) {
        uint4 u0 = *rowp(__shfl(idx0, j + sub));
        acch4(acc, u0);
    }
    if (j < deg) {                      // wave-uniform guard (R3 lesson)
        int e = j + sub;
        int ec = (e < deg) ? e : (deg - 1);
        uint4 u0 = *rowp(__shfl(idx0, ec));
        if (e < deg) acch4(acc, u0);
    }
#pragma unroll
    for (int stride = 32; stride >= 16; stride >>= 1)
#pragma unroll
        for (int v = 0; v < 4; v++) {
            int t = __shfl_xor(__builtin_bit_cast(int, acc[v]), stride);
            acc[v] = __hadd2(acc[v], __builtin_bit_cast(__half2, t));
        }

    if (lane < 16) {
        float s = invdeg[node];
        unsigned int o[4];
#pragma unroll
        for (int v = 0; v < 4; v++) {
            float2 f = __half22float2(acc[v]);
            o[v] = (unsigned int)f2h(f.x * s) | ((unsigned int)f2h(f.y * s) << 16);
        }
        *(uint4*)(outmsg + (size_t)node * 256 + lane * 8) = make_uint4(o[0], o[1], o[2], o[3]);
    }
}

// ---------------- layer-2 aggregation: offset-fp8 gather, linear decode, pk_add -----
// Per uint (4 fp8): even pair = ((w&0x00FF00FF)<<7)+0x2000_2000, odd = ((w>>1)&0x7F807F80)
// + 0x2000_2000 — 6 VALU + 2 pk_add per 4 values (vs ~32 in R7).
// acc pairing: acc[2q]=(d0,d2), acc[2q+1]=(d1,d3) of uint q.
__device__ __forceinline__ void accf8pk(__half2* a, unsigned int w) {
    unsigned int ev = ((w & 0x00FF00FFu) << 7) + 0x20002000u;
    unsigned int od = ((w >> 1) & 0x7F807F80u) + 0x20002000u;
    a[0] = __hadd2(a[0], __builtin_bit_cast(__half2, ev));
    a[1] = __hadd2(a[1], __builtin_bit_cast(__half2, od));
}
__device__ __forceinline__ void accf8x16(__half2* a, uint4 u) {
    accf8pk(a + 0, u.x); accf8pk(a + 2, u.y); accf8pk(a + 4, u.z); accf8pk(a + 6, u.w);
}

__global__ __launch_bounds__(256) void agg2_k(
    const unsigned char* __restrict__ hf8,    // h table fp8+offset: 256B rows
    const int* __restrict__ bucket, const int* __restrict__ degtot,
    const float* __restrict__ invdeg,
    unsigned short* __restrict__ outmsg)      // msg2 f16: stride 512, dims 0..255
{
    int wv = threadIdx.x >> 6, lane = threadIdx.x & 63;
    int node = blockIdx.x * 4 + wv;
    if (node >= N_NODES) return;
    int deg = degtot[node];
    int idx0 = bucket[(size_t)node * BCAP + lane];
    const int sub = lane >> 4;
    const int col = lane & 15;

    __half2 acc[8] = {};
    auto rowp = [&](int s) { return (const uint4*)(hf8 + (size_t)s * 256 + col * 16); };

    int j = 0;
    for (; j + 16 <= deg; j += 16) {
        int s0 = __shfl(idx0, j + sub),     s1 = __shfl(idx0, j + 4 + sub);
        int s2 = __shfl(idx0, j + 8 + sub), s3 = __shfl(idx0, j + 12 + sub);
        uint4 u0 = *rowp(s0), u1 = *rowp(s1), u2 = *rowp(s2), u3 = *rowp(s3);
        accf8x16(acc, u0); accf8x16(acc, u1); accf8x16(acc, u2); accf8x16(acc, u3);
    }
    for (; j + 8 <= deg; j += 8) {
        int s0 = __shfl(idx0, j + sub), s1 = __shfl(idx0, j + 4 + sub);
        uint4 u0 = *rowp(s0), u1 = *rowp(s1);
        accf8x16(acc, u0); accf8x16(acc, u1);
    }
    for (; j + 4 <= deg; j += 4) {
        uint4 u0 = *rowp(__shfl(idx0, j + sub));
        accf8x16(acc, u0);
    }
    if (j < deg) {                      // wave-uniform guard
        int e = j + sub;
        int ec = (e < deg) ? e : (deg - 1);
        uint4 u0 = *rowp(__shfl(idx0, ec));
        if (e < deg) accf8x16(acc, u0);
    }
#pragma unroll
    for (int stride = 32; stride >= 16; stride >>= 1)
#pragma unroll
        for (int v = 0; v < 8; v++) {
            int t = __shfl_xor(__builtin_bit_cast(int, acc[v]), stride);
            acc[v] = __hadd2(acc[v], __builtin_bit_cast(__half2, t));
        }

    if (lane < 16) {
        float s = invdeg[node];
        float bias = (deg > 0) ? 0.015625f : 0.0f;   // remove the +2^-6 per-neighbor offset
        unsigned int o[8];
#pragma unroll
        for (int q = 0; q < 4; q++) {
            float2 ev = __half22float2(acc[2 * q]);      // dims 4q, 4q+2
            float2 od = __half22float2(acc[2 * q + 1]);  // dims 4q+1, 4q+3
            float d0 = ev.x * s - bias, d1 = od.x * s - bias;
            float d2 = ev.y * s - bias, d3 = od.y * s - bias;
            o[2 * q]     = (unsigned int)f2h(d0) | ((unsigned int)f2h(d1) << 16);
            o[2 * q + 1] = (unsigned int)f2h(d2) | ((unsigned int)f2h(d3) << 16);
        }
        unsigned short* wp = outmsg + (size_t)node * 512 + lane * 16;
        *(uint4*)(wp)     = make_uint4(o[0], o[1], o[2], o[3]);
        *(uint4*)(wp + 8) = make_uint4(o[4], o[5], o[6], o[7]);
    }
}

// ---------------- f16 MFMA GEMM: C = relu(A(MxK) * W(256xK)^T + bias) ----------------
// 128x128 block tile, 4 waves, 2x8 16x16x32 MFMA tiles per wave. Optional fp8 side-store.
template <bool F16OUT, bool WRITE_FP8>
__global__ __launch_bounds__(256) void gemm_k(
    const unsigned short* __restrict__ A, const unsigned short* __restrict__ W,
    const float* __restrict__ bias, void* __restrict__ outp, int outStride,
    unsigned char* __restrict__ hf8, int M, int K)
{
    __shared__ __align__(16) char smem[(128 + 128) * 64];  // 16 KB
    const int t = threadIdx.x;
    const int w = t >> 6, lane = t & 63;
    const int quad = lane >> 4, l15 = lane & 15;
    const int row0 = blockIdx.x * 128;
    const int col0 = blockIdx.y * 128;

    f32x4 acc[2][8] = {};

    for (int ks = 0; ks < K; ks += 32) {
#pragma unroll
        for (int j = 0; j < 4; j++) {
            int call = w * 4 + j;        // 0..15, wave-uniform A/W split at 8
            int ci = call * 64 + lane;   // chunk id 0..1023
            const unsigned short* g;
            if (call < 8) {              // A chunks
                int rg = row0 + (ci >> 2);
                if (rg > M - 1) rg = M - 1;
                g = A + (size_t)rg * K + ks + (ci & 3) * 8;
            } else {                     // W chunks
                int c2 = ci - 512;
                g = W + (size_t)(col0 + (c2 >> 2)) * K + ks + (c2 & 3) * 8;
            }
            load_lds16(g, smem + ci * 16);
        }
        __syncthreads();

        const char* Ab = smem + (w * 32 + l15) * 64 + quad * 16;
        const char* Wb = smem + 8192 + l15 * 64 + quad * 16;
        f16x8 af0 = *(const f16x8*)(Ab);
        f16x8 af1 = *(const f16x8*)(Ab + 1024);
#pragma unroll
        for (int tt = 0; tt < 8; tt++) {
            f16x8 bfr = *(const f16x8*)(Wb + tt * 1024);
            acc[0][tt] = __builtin_amdgcn_mfma_f32_16x16x32_f16(af0, bfr, acc[0][tt], 0, 0, 0);
            acc[1][tt] = __builtin_amdgcn_mfma_f32_16x16x32_f16(af1, bfr, acc[1][tt], 0, 0, 0);
        }
        __syncthreads();
    }

#pragma unroll
    for (int g = 0; g < 2; g++) {
#pragma unroll
        for (int tt = 0; tt < 8; tt++) {
            int col = col0 + tt * 16 + l15;
            float bv = bias[col];
#pragma unroll
            for (int i = 0; i < 4; i++) {
                int row = row0 + w * 32 + g * 16 + quad * 4 + i;  // C/D: col=lane&15, row=quad*4+reg
                if (row < M) {
                    float v = fmaxf(acc[g][tt][i] + bv, 0.f);
                    size_t off = (size_t)row * outStride + col;
                    if constexpr (F16OUT) ((unsigned short*)outp)[off] = f2h(v);
                    else                  ((float*)outp)[off] = v;
                    if constexpr (WRITE_FP8) hf8[(size_t)row * 256 + col] = f2fp8o(v);
                }
            }
        }
    }
}

extern "C" void kernel_launch(void* const* d_in, const int* in_sizes, int n_in,
                              void* d_out, int out_size, void* d_ws, size_t ws_size,
                              hipStream_t stream)
{
    const float* x   = (const float*)d_in[0];
    const int*   ei  = (const int*)d_in[1];
    const float* wl1 = (const float*)d_in[2];
    const float* bl1 = (const float*)d_in[3];
    const float* wr1 = (const float*)d_in[4];
    const float* wl2 = (const float*)d_in[5];
    const float* bl2 = (const float*)d_in[6];
    const float* wr2 = (const float*)d_in[7];
    float* out = (float*)d_out;
    const int* src = ei;
    const int* dst = ei + N_EDGES;

    char* ws = (char*)d_ws;
    size_t off = 0;
    auto alloc = [&](size_t bytes) -> void* {
        void* p = ws + off;
        off = (off + bytes + 255) & ~(size_t)255;
        return p;
    };
    int*            pcnt   = (int*)           alloc((size_t)NPART * NSUB * 16 * 4);   // 1 line/cursor
    unsigned int*   pbuf   = (unsigned int*)  alloc((size_t)NPART * NSUB * SCAP * 4); // 4.8 MB
    int*            bucket = (int*)           alloc((size_t)NPART * 64 * BCAP * 4);   // 12.8 MB
    int*            degtot = (int*)           alloc((size_t)N_NODES * 4);
    float*          invdeg = (float*)         alloc((size_t)N_NODES * 4);
    unsigned short* Acat1  = (unsigned short*)alloc((size_t)N_NODES * 256 * 2);  // [msg1|x] f16
    unsigned short* Acat2  = (unsigned short*)alloc((size_t)N_NODES * 512 * 2);  // [msg2|h] f16
    unsigned char*  hf8    = (unsigned char*) alloc((size_t)N_NODES * 256);      // h fp8+offset
    unsigned short* Wcat1  = (unsigned short*)alloc((size_t)256 * 256 * 2);
    unsigned short* Wcat2  = (unsigned short*)alloc((size_t)256 * 512 * 2);

    hipMemsetAsync(pcnt, 0, (size_t)NPART * NSUB * 16 * 4, stream);
    part_append_k<<<(N_EDGES + 255) / 256, 256, 0, stream>>>(src, dst, pcnt, pbuf, N_EDGES);
    part_bucket_k<<<NPART, 256, 0, stream>>>(pcnt, pbuf, bucket, degtot, invdeg);

    cvt_x_k<<<(N_NODES * 32 + 255) / 256, 256, 0, stream>>>(x, Acat1);
    cvt_w_k<<<(256 * 256 + 255) / 256, 256, 0, stream>>>(wl1, wr1, Wcat1, 128);
    cvt_w_k<<<(256 * 512 + 255) / 256, 256, 0, stream>>>(wl2, wr2, Wcat2, 256);

    // Layer 1: agg x_f16 -> msg1; h = relu(Acat1 @ Wcat1^T + b) -> Acat2 right half (f16) + hf8
    agg1_k<<<(N_NODES + 3) / 4, 256, 0, stream>>>(
        Acat1 + 128, bucket, degtot, invdeg, Acat1);
    gemm_k<true, true><<<dim3((N_NODES + 127) / 128, 2), 256, 0, stream>>>(
        Acat1, Wcat1, bl1, (void*)(Acat2 + 256), 512, hf8, N_NODES, 256);

    // Layer 2: agg hf8 -> msg2; out = relu(Acat2 @ Wcat2^T + b) fp32
    agg2_k<<<(N_NODES + 3) / 4, 256, 0, stream>>>(
        hf8, bucket, degtot, invdeg, Acat2);
    gemm_k<false, false><<<dim3((N_NODES + 127) / 128, 2), 256, 0, stream>>>(
        Acat2, Wcat2, bl2, (void*)out, 256, nullptr, N_NODES, 512);
}

// Round 9
// 275.834 us; speedup vs baseline: 2.0397x; 1.0447x over previous
//
#include <hip/hip_runtime.h>
#include <hip/hip_fp16.h>
#include <stdint.h>

#define N_NODES 50000
#define N_EDGES 800000
#define BCAP 64    // Poisson(16): P(deg>64) ~ 1e-22 — clamp is safe
#define NPART 782  // ceil(50000/64) dst-range partitions, 64 nodes each
#define NSUB 4     // sub-lists per partition -> 3128 cursors, one 64B line each
#define SCAP 384   // per-sub-list capacity: Poisson(256) + 8 sigma

typedef _Float16 f16x8 __attribute__((ext_vector_type(8)));
typedef __attribute__((ext_vector_type(4))) float f32x4;

__device__ __forceinline__ unsigned short f2h(float f) {
    return __builtin_bit_cast(unsigned short, (_Float16)f);
}

// fp8 e4m3 with +2^-6 offset (inputs >= 0 post-relu): code is ALWAYS normal (c>=8),
// so decode is exactly linear in bits: f16 = (c<<7) + 0x2000. The +2^-6 telescopes
// to a per-node constant removed after reduction. v=0 roundtrips exactly.
__device__ __forceinline__ unsigned char f2fp8o(float v) {
    v = fminf(v, 440.f) + 0.015625f;
    unsigned int u = __builtin_bit_cast(unsigned int, v);
    u += 0x7FFFFu + ((u >> 20) & 1u);            // RNE to 3 mantissa bits
    return (unsigned char)((u >> 20) - 960u);    // ((exp-120)<<3)|mant3, 8..126
}

__device__ __forceinline__ void load_lds16(const void* g, void* l) {
    __builtin_amdgcn_global_load_lds(
        (const __attribute__((address_space(1))) void*)(uintptr_t)g,
        (__attribute__((address_space(3))) void*)(unsigned int)(uintptr_t)l,
        16, 0, 0);
}

// ---------------- build pass A: append edges into (partition,sub) lists --------------
// R6 lesson: same-line atomic serialization ~8.8ns/op; cost ∝ ops per cursor LINE.
__global__ __launch_bounds__(256) void part_append_k(
    const int* __restrict__ src, const int* __restrict__ dst,
    int* __restrict__ pcnt, unsigned int* __restrict__ pbuf, int nedges)
{
    int e = blockIdx.x * 256 + threadIdx.x;
    if (e >= nedges) return;
    int s = src[e], d = dst[e];
    int cidx = (d >> 6) * NSUB + (e & (NSUB - 1));
    int pos = atomicAdd(&pcnt[cidx * 16], 1);   // *16: one 64B line per cursor
    if (pos < SCAP)
        pbuf[(size_t)cidx * SCAP + pos] = ((unsigned)(d & 63) << 16) | (unsigned)s;
}

// ---------------- build pass B: per-partition local bucket fill (LDS counters) --------
__global__ __launch_bounds__(256) void part_bucket_k(
    const int* __restrict__ pcnt, const unsigned int* __restrict__ pbuf,
    int* __restrict__ bucket, int* __restrict__ degtot, float* __restrict__ invdeg)
{
    __shared__ int lcnt[64];
    int part = blockIdx.x, tid = threadIdx.x;
    if (tid < 64) lcnt[tid] = 0;
    __syncthreads();
#pragma unroll
    for (int sub = 0; sub < NSUB; sub++) {
        int cidx = part * NSUB + sub;
        int n = pcnt[cidx * 16];
        if (n > SCAP) n = SCAP;
        const unsigned int* pb = pbuf + (size_t)cidx * SCAP;
        for (int i = tid; i < n; i += 256) {
            unsigned int en = pb[i];
            int dlow = (int)(en >> 16), s = (int)(en & 0xFFFFu);
            int p = atomicAdd(&lcnt[dlow], 1);
            if (p < BCAP) bucket[(size_t)(part * 64 + dlow) * BCAP + p] = s;
        }
    }
    __syncthreads();
    if (tid < 64) {
        int node = part * 64 + tid;
        if (node < N_NODES) {
            int c = lcnt[tid];
            degtot[node] = (c > BCAP) ? BCAP : c;
            invdeg[node] = 1.0f / (float)(c > 1 ? c : 1);
        }
    }
}

// ---------------- converts (f16 tables) ----------------
__global__ __launch_bounds__(256) void cvt_x_k(
    const float* __restrict__ x, unsigned short* __restrict__ dst)
{
    int tid = blockIdx.x * 256 + threadIdx.x;  // one per 4 floats
    if (tid >= N_NODES * 32) return;
    int row = tid >> 5, c = (tid & 31) * 4;
    float4 v = *(const float4*)(x + (size_t)row * 128 + c);
    ushort4 o;
    o.x = f2h(v.x); o.y = f2h(v.y); o.z = f2h(v.z); o.w = f2h(v.w);
    *(ushort4*)(dst + (size_t)row * 256 + 128 + c) = o;
}

__global__ __launch_bounds__(256) void cvt_w_k(
    const float* __restrict__ wl, const float* __restrict__ wr,
    unsigned short* __restrict__ dst, int Keach)
{
    int tid = blockIdx.x * 256 + threadIdx.x;
    if (tid >= 256 * 2 * Keach) return;
    int n = tid / (2 * Keach), k = tid - n * 2 * Keach;
    float v = (k < Keach) ? wl[(size_t)n * Keach + k]
                          : wr[(size_t)n * Keach + (k - Keach)];
    dst[tid] = f2h(v);
}

// ---------------- layer-1 aggregation: f16 gather, packed-f16 accumulate ------------
__device__ __forceinline__ void acch4(__half2* a, uint4 u) {
    a[0] = __hadd2(a[0], __builtin_bit_cast(__half2, u.x));
    a[1] = __hadd2(a[1], __builtin_bit_cast(__half2, u.y));
    a[2] = __hadd2(a[2], __builtin_bit_cast(__half2, u.z));
    a[3] = __hadd2(a[3], __builtin_bit_cast(__half2, u.w));
}

__global__ __launch_bounds__(256) void agg1_k(
    const unsigned short* __restrict__ feat,
    const int* __restrict__ bucket, const int* __restrict__ degtot,
    const float* __restrict__ invdeg,
    unsigned short* __restrict__ outmsg)
{
    int wv = threadIdx.x >> 6, lane = threadIdx.x & 63;
    int node = blockIdx.x * 4 + wv;
    if (node >= N_NODES) return;
    int deg = degtot[node];
    int idx0 = bucket[(size_t)node * BCAP + lane];
    const int sub = lane >> 4;
    const int col = lane & 15;

    __half2 acc[4] = {};
    auto rowp = [&](int s) { return (const uint4*)(feat + (size_t)s * 256 + col * 8); };

    int j = 0;
    for (; j + 16 <= deg; j += 16) {
        int s0 = __shfl(idx0, j + sub),     s1 = __shfl(idx0, j + 4 + sub);
        int s2 = __shfl(idx0, j + 8 + sub), s3 = __shfl(idx0, j + 12 + sub);
        uint4 u0 = *rowp(s0), u1 = *rowp(s1), u2 = *rowp(s2), u3 = *rowp(s3);
        acch4(acc, u0); acch4(acc, u1); acch4(acc, u2); acch4(acc, u3);
    }
    for (; j + 8 <= deg; j += 8) {
        int s0 = __shfl(idx0, j + sub), s1 = __shfl(idx0, j + 4 + sub);
        uint4 u0 = *rowp(s0), u1 = *rowp(s1);
        acch4(acc, u0); acch4(acc, u1);
    }
    for (; j + 4 <= deg; j += 4) {
        uint4 u0 = *rowp(__shfl(idx0, j + sub));
        acch4(acc, u0);
    }
    if (j < deg) {                      // wave-uniform guard (R3 lesson)
        int e = j + sub;
        int ec = (e < deg) ? e : (deg - 1);
        uint4 u0 = *rowp(__shfl(idx0, ec));
        if (e < deg) acch4(acc, u0);
    }
#pragma unroll
    for (int stride = 32; stride >= 16; stride >>= 1)
#pragma unroll
        for (int v = 0; v < 4; v++) {
            int t = __shfl_xor(__builtin_bit_cast(int, acc[v]), stride);
            acc[v] = __hadd2(acc[v], __builtin_bit_cast(__half2, t));
        }

    if (lane < 16) {
        float s = invdeg[node];
        unsigned int o[4];
#pragma unroll
        for (int v = 0; v < 4; v++) {
            float2 f = __half22float2(acc[v]);
            o[v] = (unsigned int)f2h(f.x * s) | ((unsigned int)f2h(f.y * s) << 16);
        }
        *(uint4*)(outmsg + (size_t)node * 256 + lane * 8) = make_uint4(o[0], o[1], o[2], o[3]);
    }
}

// ---------------- layer-2 aggregation: offset-fp8 gather, linear decode, pk_add -----
__device__ __forceinline__ void accf8pk(__half2* a, unsigned int w) {
    unsigned int ev = ((w & 0x00FF00FFu) << 7) + 0x20002000u;
    unsigned int od = ((w >> 1) & 0x7F807F80u) + 0x20002000u;
    a[0] = __hadd2(a[0], __builtin_bit_cast(__half2, ev));
    a[1] = __hadd2(a[1], __builtin_bit_cast(__half2, od));
}
__device__ __forceinline__ void accf8x16(__half2* a, uint4 u) {
    accf8pk(a + 0, u.x); accf8pk(a + 2, u.y); accf8pk(a + 4, u.z); accf8pk(a + 6, u.w);
}

__global__ __launch_bounds__(256) void agg2_k(
    const unsigned char* __restrict__ hf8,
    const int* __restrict__ bucket, const int* __restrict__ degtot,
    const float* __restrict__ invdeg,
    unsigned short* __restrict__ outmsg)
{
    int wv = threadIdx.x >> 6, lane = threadIdx.x & 63;
    int node = blockIdx.x * 4 + wv;
    if (node >= N_NODES) return;
    int deg = degtot[node];
    int idx0 = bucket[(size_t)node * BCAP + lane];
    const int sub = lane >> 4;
    const int col = lane & 15;

    __half2 acc[8] = {};
    auto rowp = [&](int s) { return (const uint4*)(hf8 + (size_t)s * 256 + col * 16); };

    int j = 0;
    for (; j + 16 <= deg; j += 16) {
        int s0 = __shfl(idx0, j + sub),     s1 = __shfl(idx0, j + 4 + sub);
        int s2 = __shfl(idx0, j + 8 + sub), s3 = __shfl(idx0, j + 12 + sub);
        uint4 u0 = *rowp(s0), u1 = *rowp(s1), u2 = *rowp(s2), u3 = *rowp(s3);
        accf8x16(acc, u0); accf8x16(acc, u1); accf8x16(acc, u2); accf8x16(acc, u3);
    }
    for (; j + 8 <= deg; j += 8) {
        int s0 = __shfl(idx0, j + sub), s1 = __shfl(idx0, j + 4 + sub);
        uint4 u0 = *rowp(s0), u1 = *rowp(s1);
        accf8x16(acc, u0); accf8x16(acc, u1);
    }
    for (; j + 4 <= deg; j += 4) {
        uint4 u0 = *rowp(__shfl(idx0, j + sub));
        accf8x16(acc, u0);
    }
    if (j < deg) {
        int e = j + sub;
        int ec = (e < deg) ? e : (deg - 1);
        uint4 u0 = *rowp(__shfl(idx0, ec));
        if (e < deg) accf8x16(acc, u0);
    }
#pragma unroll
    for (int stride = 32; stride >= 16; stride >>= 1)
#pragma unroll
        for (int v = 0; v < 8; v++) {
            int t = __shfl_xor(__builtin_bit_cast(int, acc[v]), stride);
            acc[v] = __hadd2(acc[v], __builtin_bit_cast(__half2, t));
        }

    if (lane < 16) {
        float s = invdeg[node];
        float bias = (deg > 0) ? 0.015625f : 0.0f;
        unsigned int o[8];
#pragma unroll
        for (int q = 0; q < 4; q++) {
            float2 ev = __half22float2(acc[2 * q]);
            float2 od = __half22float2(acc[2 * q + 1]);
            float d0 = ev.x * s - bias, d1 = od.x * s - bias;
            float d2 = ev.y * s - bias, d3 = od.y * s - bias;
            o[2 * q]     = (unsigned int)f2h(d0) | ((unsigned int)f2h(d1) << 16);
            o[2 * q + 1] = (unsigned int)f2h(d2) | ((unsigned int)f2h(d3) << 16);
        }
        unsigned short* wp = outmsg + (size_t)node * 512 + lane * 16;
        *(uint4*)(wp)     = make_uint4(o[0], o[1], o[2], o[3]);
        *(uint4*)(wp + 8) = make_uint4(o[4], o[5], o[6], o[7]);
    }
}

// ---------------- f16 MFMA GEMM, double-buffered LDS ----------------
// R8 lesson: stage->barrier->compute->barrier exposes full global->LDS latency each
// K-iter (MfmaUtil 9%, 3x memory floor). Now: prefetch tile i+1 into buf^1 BEFORE
// computing tile i; ONE barrier per iter (its vmcnt(0) drains a prefetch that had the
// whole compute phase in flight). LDS 2x16KB -> ~4 blocks/CU of independent overlap.
template <bool F16OUT, bool WRITE_FP8>
__global__ __launch_bounds__(256) void gemm_k(
    const unsigned short* __restrict__ A, const unsigned short* __restrict__ W,
    const float* __restrict__ bias, void* __restrict__ outp, int outStride,
    unsigned char* __restrict__ hf8, int M, int K)
{
    __shared__ __align__(16) char smem[2 * 16384];  // 32 KB: two 16KB tile buffers
    const int t = threadIdx.x;
    const int w = t >> 6, lane = t & 63;
    const int quad = lane >> 4, l15 = lane & 15;
    const int row0 = blockIdx.x * 128;
    const int col0 = blockIdx.y * 128;
    const int niter = K >> 5;

    auto stage = [&](int buf, int ks) {
#pragma unroll
        for (int j = 0; j < 4; j++) {
            int call = w * 4 + j;        // 0..15, wave-uniform A/W split at 8
            int ci = call * 64 + lane;   // chunk id 0..1023
            const unsigned short* g;
            if (call < 8) {              // A chunks
                int rg = row0 + (ci >> 2);
                if (rg > M - 1) rg = M - 1;
                g = A + (size_t)rg * K + ks + (ci & 3) * 8;
            } else {                     // W chunks
                int c2 = ci - 512;
                g = W + (size_t)(col0 + (c2 >> 2)) * K + ks + (c2 & 3) * 8;
            }
            load_lds16(g, smem + buf * 16384 + ci * 16);
        }
    };

    f32x4 acc[2][8] = {};

    stage(0, 0);
    __syncthreads();                     // tile 0 ready

    for (int i = 0; i < niter; i++) {
        if (i + 1 < niter) stage((i + 1) & 1, (i + 1) << 5);   // async prefetch

        const char* base = smem + (i & 1) * 16384;
        const char* Ab = base + (w * 32 + l15) * 64 + quad * 16;
        const char* Wb = base + 8192 + l15 * 64 + quad * 16;
        f16x8 af0 = *(const f16x8*)(Ab);
        f16x8 af1 = *(const f16x8*)(Ab + 1024);
#pragma unroll
        for (int tt = 0; tt < 8; tt++) {
            f16x8 bfr = *(const f16x8*)(Wb + tt * 1024);
            acc[0][tt] = __builtin_amdgcn_mfma_f32_16x16x32_f16(af0, bfr, acc[0][tt], 0, 0, 0);
            acc[1][tt] = __builtin_amdgcn_mfma_f32_16x16x32_f16(af1, bfr, acc[1][tt], 0, 0, 0);
        }
        __syncthreads();                 // drains prefetch; frees buf (i&1) for iter i+1
    }

#pragma unroll
    for (int g = 0; g < 2; g++) {
#pragma unroll
        for (int tt = 0; tt < 8; tt++) {
            int col = col0 + tt * 16 + l15;
            float bv = bias[col];
#pragma unroll
            for (int i = 0; i < 4; i++) {
                int row = row0 + w * 32 + g * 16 + quad * 4 + i;  // C/D: col=lane&15, row=quad*4+reg
                if (row < M) {
                    float v = fmaxf(acc[g][tt][i] + bv, 0.f);
                    size_t off = (size_t)row * outStride + col;
                    if constexpr (F16OUT) ((unsigned short*)outp)[off] = f2h(v);
                    else                  ((float*)outp)[off] = v;
                    if constexpr (WRITE_FP8) hf8[(size_t)row * 256 + col] = f2fp8o(v);
                }
            }
        }
    }
}

extern "C" void kernel_launch(void* const* d_in, const int* in_sizes, int n_in,
                              void* d_out, int out_size, void* d_ws, size_t ws_size,
                              hipStream_t stream)
{
    const float* x   = (const float*)d_in[0];
    const int*   ei  = (const int*)d_in[1];
    const float* wl1 = (const float*)d_in[2];
    const float* bl1 = (const float*)d_in[3];
    const float* wr1 = (const float*)d_in[4];
    const float* wl2 = (const float*)d_in[5];
    const float* bl2 = (const float*)d_in[6];
    const float* wr2 = (const float*)d_in[7];
    float* out = (float*)d_out;
    const int* src = ei;
    const int* dst = ei + N_EDGES;

    char* ws = (char*)d_ws;
    size_t off = 0;
    auto alloc = [&](size_t bytes) -> void* {
        void* p = ws + off;
        off = (off + bytes + 255) & ~(size_t)255;
        return p;
    };
    int*            pcnt   = (int*)           alloc((size_t)NPART * NSUB * 16 * 4);
    unsigned int*   pbuf   = (unsigned int*)  alloc((size_t)NPART * NSUB * SCAP * 4);
    int*            bucket = (int*)           alloc((size_t)NPART * 64 * BCAP * 4);
    int*            degtot = (int*)           alloc((size_t)N_NODES * 4);
    float*          invdeg = (float*)         alloc((size_t)N_NODES * 4);
    unsigned short* Acat1  = (unsigned short*)alloc((size_t)N_NODES * 256 * 2);  // [msg1|x] f16
    unsigned short* Acat2  = (unsigned short*)alloc((size_t)N_NODES * 512 * 2);  // [msg2|h] f16
    unsigned char*  hf8    = (unsigned char*) alloc((size_t)N_NODES * 256);      // h fp8+offset
    unsigned short* Wcat1  = (unsigned short*)alloc((size_t)256 * 256 * 2);
    unsigned short* Wcat2  = (unsigned short*)alloc((size_t)256 * 512 * 2);

    hipMemsetAsync(pcnt, 0, (size_t)NPART * NSUB * 16 * 4, stream);
    part_append_k<<<(N_EDGES + 255) / 256, 256, 0, stream>>>(src, dst, pcnt, pbuf, N_EDGES);
    part_bucket_k<<<NPART, 256, 0, stream>>>(pcnt, pbuf, bucket, degtot, invdeg);

    cvt_x_k<<<(N_NODES * 32 + 255) / 256, 256, 0, stream>>>(x, Acat1);
    cvt_w_k<<<(256 * 256 + 255) / 256, 256, 0, stream>>>(wl1, wr1, Wcat1, 128);
    cvt_w_k<<<(256 * 512 + 255) / 256, 256, 0, stream>>>(wl2, wr2, Wcat2, 256);

    // Layer 1: agg x_f16 -> msg1; h = relu(Acat1 @ Wcat1^T + b) -> Acat2 right half (f16) + hf8
    agg1_k<<<(N_NODES + 3) / 4, 256, 0, stream>>>(
        Acat1 + 128, bucket, degtot, invdeg, Acat1);
    gemm_k<true, true><<<dim3((N_NODES + 127) / 128, 2), 256, 0, stream>>>(
        Acat1, Wcat1, bl1, (void*)(Acat2 + 256), 512, hf8, N_NODES, 256);

    // Layer 2: agg hf8 -> msg2; out = relu(Acat2 @ Wcat2^T + b) fp32
    agg2_k<<<(N_NODES + 3) / 4, 256, 0, stream>>>(
        hf8, bucket, degtot, invdeg, Acat2);
    gemm_k<false, false><<<dim3((N_NODES + 127) / 128, 2), 256, 0, stream>>>(
        Acat2, Wcat2, bl2, (void*)out, 256, nullptr, N_NODES, 512);
}